// Round 13
// baseline (316.482 us; speedup 1.0000x reference)
//
#include <hip/hip_runtime.h>
#include <hip/hip_bf16.h>

#define SDIM 48
#define SP   110592           // 48^3
#define C_IN 16
#define O_OUT 32
#define T27  27
#define OST  96               // offs row stride (channel-last, 81 used, 96 padded)
#define OLROW 100             // offset-LDS row stride (ush) -> conflict-free
#define CPST 36               // Cp row stride (floats) -> 2-way-max banks

typedef __attribute__((ext_vector_type(8))) short bf16x8;
typedef __attribute__((ext_vector_type(4))) float f32x4;

__device__ __forceinline__ float bf2f(unsigned short u) {
    unsigned int x = ((unsigned int)u) << 16;
    return __builtin_bit_cast(float, x);
}
__device__ __forceinline__ unsigned short f2bf(float f) {
    unsigned int x = __builtin_bit_cast(unsigned int, f);
    x += 0x7fffu + ((x >> 16) & 1u);     // RNE
    return (unsigned short)(x >> 16);
}

// ---------- Kernel 0a: x [n][c][sp] fp32 -> xTf [n][sp][c] fp32 --------------
__global__ __launch_bounds__(256)
void prep_xTf(const float* __restrict__ x, float* __restrict__ xTf) {
    __shared__ float l[256 * 17];
    const int tid = threadIdx.x;
    const int b   = blockIdx.x;          // 0..863
    const int n   = b / 432;
    const int sp0 = (b - n * 432) * 256;
    #pragma unroll
    for (int c = 0; c < 16; ++c)
        l[tid * 17 + c] = x[((size_t)(n * 16 + c)) * SP + sp0 + tid];
    __syncthreads();
    float4* dst = (float4*)(xTf + ((size_t)(n * SP + sp0 + tid)) * 16);
    #pragma unroll
    for (int q = 0; q < 4; ++q)
        dst[q] = make_float4(l[tid * 17 + 4 * q],     l[tid * 17 + 4 * q + 1],
                             l[tid * 17 + 4 * q + 2], l[tid * 17 + 4 * q + 3]);
}

// ---------- Kernel 0b: pack offset-conv weights into B-fragment layout -------
__global__ __launch_bounds__(256)
void prep_bfrag(const float* __restrict__ ow, unsigned short* __restrict__ Bf) {
    int idx = blockIdx.x * 256 + threadIdx.x;     // 0..43007
    int r    = idx & 7;
    int lane = (idx >> 3) & 63;
    int snt  = idx >> 9;                          // s*6+nt, 0..83
    int s = snt / 6, nt = snt - s * 6;
    int kk  = ((lane >> 4) << 3) + r;
    int g   = nt * 16 + (lane & 15);
    int tap = 2 * s + (kk >> 4);
    int c   = kk & 15;
    float v = 0.f;
    if (tap < 27 && g < 81) v = ow[((size_t)(g * 16 + c)) * 27 + tap];
    Bf[idx] = f2bf(v);
}

// ---------- Kernel 0c: pack einsum weights into B-frag layout (14 k-steps) ---
__global__ __launch_bounds__(256)
void prep_wfrag(const float* __restrict__ w, unsigned short* __restrict__ Wf) {
    int idx = blockIdx.x * 256 + threadIdx.x;     // 0..14335
    int r    = idx & 7;
    int lane = (idx >> 3) & 63;
    int snt  = idx >> 9;                          // s*2+nt, 0..27
    int s = snt >> 1, nt = snt & 1;
    int kk  = ((lane >> 4) << 3) + r;
    int o   = nt * 16 + (lane & 15);
    int tap = 2 * s + (kk >> 4);
    int c   = kk & 15;
    float v = 0.f;
    if (tap < 27) v = w[((size_t)(o * 16 + c)) * 27 + tap];
    Wf[idx] = f2bf(v);
}

// ---------- Kernel 1: offset conv as implicit-GEMM MFMA ----------------------
// Stages A-tiles from f32 xTf (cvt_pk to bf16 inline). Output: offs[n][sp][96]
// bf16 channel-last, contiguous 12KB tile store.
__global__ __launch_bounds__(256)
void offs_conv_mfma(const float* __restrict__ xTf,
                    const unsigned short* __restrict__ Bf,
                    const float* __restrict__ ob,
                    unsigned short* __restrict__ offs) {
    __shared__ unsigned short Alds[256 * 8];      // 4KB staging
    __shared__ unsigned short Tl[64 * 104];       // 13KB epilogue transpose
    const int tid  = threadIdx.x;
    const int lane = tid & 63;
    const int wid  = tid >> 6;
    // XCD-aware chunked swizzle: 3456 = 8 x 432
    const int bid  = (blockIdx.x & 7) * 432 + (blockIdx.x >> 3);
    const int m    = tid & 63;
    const int n    = (bid >= 1728) ? 1 : 0;
    const int sp   = bid * 64 + m - n * SP;
    const int z    = sp / 2304;
    const int rem  = sp - z * 2304;
    const int y    = rem / 48;
    const int xx   = rem - y * 48;
    const int tapoff = wid >> 1;
    const int half   = wid & 1;

    auto stage_load = [&](int s) -> uint4 {
        int tap = 2 * s + tapoff;
        int kd = tap / 9;
        int t2 = tap - kd * 9;
        int kh = t2 / 3;
        int kw = t2 - kh * 3;
        int di = z + kd - 1, hi = y + kh - 1, wi = xx + kw - 1;
        bool ok = (tap < 27) && ((unsigned)di < 48u) && ((unsigned)hi < 48u) &&
                  ((unsigned)wi < 48u);
        uint4 v = make_uint4(0u, 0u, 0u, 0u);
        if (ok) {
            const float4* p = (const float4*)(xTf +
                ((size_t)(n * SP + (di * 2304 + hi * 48 + wi))) * 16 + half * 8);
            float4 v0 = p[0];
            float4 v1 = p[1];
            unsigned int r0, r1, r2, r3;
            asm("v_cvt_pk_bf16_f32 %0, %1, %2" : "=v"(r0) : "v"(v0.x), "v"(v0.y));
            asm("v_cvt_pk_bf16_f32 %0, %1, %2" : "=v"(r1) : "v"(v0.z), "v"(v0.w));
            asm("v_cvt_pk_bf16_f32 %0, %1, %2" : "=v"(r2) : "v"(v1.x), "v"(v1.y));
            asm("v_cvt_pk_bf16_f32 %0, %1, %2" : "=v"(r3) : "v"(v1.z), "v"(v1.w));
            v = make_uint4(r0, r1, r2, r3);
        }
        return v;
    };

    f32x4 acc[6];
    #pragma unroll
    for (int t = 0; t < 6; ++t) acc[t] = (f32x4){0.f, 0.f, 0.f, 0.f};

    uint4 v = stage_load(0);
    for (int s = 0; s < 14; ++s) {
        __syncthreads();
        *(uint4*)&Alds[tid * 8] = v;
        __syncthreads();
        if (s < 13) v = stage_load(s + 1);        // prefetch overlaps MFMA
        bf16x8 a = *(const bf16x8*)&Alds[(((lane >> 4) * 64) + (wid * 16) + (lane & 15)) * 8];
        const bf16x8* bp = (const bf16x8*)Bf + (size_t)(s * 6) * 64 + lane;
        #pragma unroll
        for (int nt = 0; nt < 6; ++nt) {
            bf16x8 b = bp[nt * 64];
            acc[nt] = __builtin_amdgcn_mfma_f32_16x16x32_bf16(a, b, acc[nt], 0, 0, 0);
        }
    }

    // epilogue: bias + bf16 into LDS [row][g] (stride 104), then contiguous out
    const int mrow = wid * 16 + ((lane >> 4) << 2);
    #pragma unroll
    for (int nt = 0; nt < 6; ++nt) {
        int g = nt * 16 + (lane & 15);
        float bia = (g < 81) ? ob[g] : 0.f;
        #pragma unroll
        for (int r = 0; r < 4; ++r)
            Tl[(mrow + r) * 104 + g] = f2bf(acc[nt][r] + bia);
    }
    __syncthreads();
    unsigned short* dst = offs + (size_t)bid * (64 * OST);
    #pragma unroll
    for (int k = 0; k < 3; ++k) {
        int idx = k * 256 + tid;                  // 0..767 uint4-chunks
        int row = idx / 12;
        int col = (idx - row * 12) * 8;
        uint4 vv = *(const uint4*)&Tl[row * 104 + col];
        *(uint4*)(dst + row * OST + col) = vv;
    }
}

// ---------- Kernel 2: wave-independent fused sampling, f32 gathers -----------
// 448 threads = 7 waves; wave wv owns k-steps {2wv, 2wv+1} for both point
// groups (p = pg*16 + lane&15). Lane samples exactly its A-fragment from
// f32 xTf: 8 corners x 2 float4 loads, pk-fma directly (NO bf16 unpack —
// that was 64 VALU ops/half-sample, 36% of the stream). cvt to bf16 once.
// REGISTER-CAP HISTORY (do not tighten): cap<=64 on this sampler spills
// (R5: FETCH x7, R9: WRITE x5). (448,4) -> cap 128.
__global__ __launch_bounds__(448, 4)
void deform_fused(const float* __restrict__ xTf,
                  const unsigned short* __restrict__ Wf,
                  const unsigned short* __restrict__ offs,
                  float* __restrict__ out) {
    __shared__ unsigned short OLDS[32 * OLROW];   // 6.4KB offsets
    __shared__ float Cp[7 * 32 * CPST];           // 32.3KB partial-C

    const int tid  = threadIdx.x;
    const int lane = tid & 63;
    const int wv   = tid >> 6;                    // wave 0..6
    const int pl   = lane & 15;                   // point-local (A-frag row)
    const int chh  = (lane >> 4) & 1;             // channel half
    const int tl   = lane >> 5;                   // tap-local in k-step
    // XCD-aware chunked swizzle: 6912 = 8 x 864
    const int bid  = (blockIdx.x & 7) * 864 + (blockIdx.x >> 3);
    const int n    = (bid >= 3456) ? 1 : 0;
    const int sp0  = bid * 32 - n * SP;

    // ---- phase 0: coalesced offset preload (32 rows x 96 ush = 384 uint4) --
    if (tid < 384) {
        int row = tid / 12;
        int col = (tid - row * 12) * 8;
        uint4 v = *(const uint4*)(offs + ((size_t)(n * SP + sp0 + row)) * OST + col);
        *(uint4*)&OLDS[row * OLROW + col] = v;
    }
    __syncthreads();

    const f32x4* xf4 = (const f32x4*)(xTf + (size_t)n * SP * 16);

    f32x4 acc[2][2];                              // [pg][ntile]
    #pragma unroll
    for (int a_ = 0; a_ < 2; ++a_)
        #pragma unroll
        for (int b_ = 0; b_ < 2; ++b_) acc[a_][b_] = (f32x4){0.f, 0.f, 0.f, 0.f};

    #pragma unroll
    for (int pg = 0; pg < 2; ++pg) {
        const int p  = pg * 16 + pl;
        const int sp = sp0 + p;
        const int z  = sp / 2304;
        const int rm = sp - z * 2304;
        const int y  = rm / 48;
        const int xx = rm - y * 48;

        #pragma unroll
        for (int s2 = 0; s2 < 2; ++s2) {
            const int s   = 2 * wv + s2;          // k-step 0..13
            const int tap = 2 * s + tl;           // 0..27 (27 = zero pad)
            uint4 au = make_uint4(0u, 0u, 0u, 0u);
            if (tap < 27) {
                const int kd = tap / 9;
                const int t2 = tap - kd * 9;
                const int kh = t2 / 3;
                const int kw = t2 - kh * 3;
                float pd = (float)(z + kd - 1)  + bf2f(OLDS[p * OLROW + tap]);
                float ph = (float)(y + kh - 1)  + bf2f(OLDS[p * OLROW + 27 + tap]);
                float pw = (float)(xx + kw - 1) + bf2f(OLDS[p * OLROW + 54 + tap]);
                float df = floorf(pd), hf = floorf(ph), wf = floorf(pw);
                float fd = pd - df, fh = ph - hf, fw = pw - wf;
                int d0 = (int)df, h0 = (int)hf, w0 = (int)wf;
                float wd0 = ((unsigned)d0       < 48u) ? (1.f - fd) : 0.f;
                float wd1 = ((unsigned)(d0 + 1) < 48u) ? fd : 0.f;
                float wh0 = ((unsigned)h0       < 48u) ? (1.f - fh) : 0.f;
                float wh1 = ((unsigned)(h0 + 1) < 48u) ? fh : 0.f;
                float ww0 = ((unsigned)w0       < 48u) ? (1.f - fw) : 0.f;
                float ww1 = ((unsigned)(w0 + 1) < 48u) ? fw : 0.f;
                int dc0 = min(max(d0,     0), 47) * 2304;
                int dc1 = min(max(d0 + 1, 0), 47) * 2304;
                int hc0 = min(max(h0,     0), 47) * 48;
                int hc1 = min(max(h0 + 1, 0), 47) * 48;
                int wc0 = min(max(w0,     0), 47);
                int wc1 = min(max(w0 + 1, 0), 47);

                float wdh[4] = {wd0 * wh0, wd0 * wh1, wd1 * wh0, wd1 * wh1};
                int   rdh[4] = {dc0 + hc0, dc0 + hc1, dc1 + hc0, dc1 + hc1};

                f32x4 s4a = (f32x4){0.f, 0.f, 0.f, 0.f};
                f32x4 s4b = (f32x4){0.f, 0.f, 0.f, 0.f};

                #pragma unroll
                for (int g2 = 0; g2 < 2; ++g2) {  // 2 batches of 4 corners
                    f32x4 c0[4], c1[4];
                    float cw[4];
                    #pragma unroll
                    for (int jj = 0; jj < 4; ++jj) {
                        int cj = g2 * 4 + jj;
                        int dh = cj >> 1;
                        int ws_ = cj & 1;
                        int idx = rdh[dh] + (ws_ ? wc1 : wc0);
                        const f32x4* cp = xf4 + (size_t)idx * 4 + chh * 2;
                        c0[jj] = cp[0];
                        c1[jj] = cp[1];
                        cw[jj] = wdh[dh] * (ws_ ? ww1 : ww0);
                    }
                    #pragma unroll
                    for (int jj = 0; jj < 4; ++jj) {
                        f32x4 w4 = (f32x4){cw[jj], cw[jj], cw[jj], cw[jj]};
                        s4a = __builtin_elementwise_fma(c0[jj], w4, s4a);
                        s4b = __builtin_elementwise_fma(c1[jj], w4, s4b);
                    }
                }
                unsigned int o0, o1, o2, o3;
                asm("v_cvt_pk_bf16_f32 %0, %1, %2" : "=v"(o0) : "v"(s4a[0]), "v"(s4a[1]));
                asm("v_cvt_pk_bf16_f32 %0, %1, %2" : "=v"(o1) : "v"(s4a[2]), "v"(s4a[3]));
                asm("v_cvt_pk_bf16_f32 %0, %1, %2" : "=v"(o2) : "v"(s4b[0]), "v"(s4b[1]));
                asm("v_cvt_pk_bf16_f32 %0, %1, %2" : "=v"(o3) : "v"(s4b[2]), "v"(s4b[3]));
                au = make_uint4(o0, o1, o2, o3);
            }
            bf16x8 a = __builtin_bit_cast(bf16x8, au);
            const bf16x8* bp = (const bf16x8*)Wf + (size_t)(s * 2) * 64 + lane;
            acc[pg][0] = __builtin_amdgcn_mfma_f32_16x16x32_bf16(a, bp[0],  acc[pg][0], 0, 0, 0);
            acc[pg][1] = __builtin_amdgcn_mfma_f32_16x16x32_bf16(a, bp[64], acc[pg][1], 0, 0, 0);
        }
    }

    // ---- tail: partial-C write + fp32 reduce + store ----
    {
        const int o16 = lane & 15;
        const int m0  = (lane >> 4) << 2;
        #pragma unroll
        for (int pg = 0; pg < 2; ++pg) {
            *(f32x4*)&Cp[(wv * 32 + o16)      * CPST + pg * 16 + m0] = acc[pg][0];
            *(f32x4*)&Cp[(wv * 32 + 16 + o16) * CPST + pg * 16 + m0] = acc[pg][1];
        }
    }
    __syncthreads();

    #pragma unroll
    for (int rep = 0; rep < 3; ++rep) {
        int i = tid + rep * 448;
        if (i < 1024) {
            int o = i >> 5;                       // 0..31
            int m = i & 31;
            float r0 = 0.f;
            #pragma unroll
            for (int w2 = 0; w2 < 7; ++w2)
                r0 += Cp[(w2 * 32 + o) * CPST + m];
            out[((size_t)(n * O_OUT + o)) * SP + sp0 + m] = r0;
        }
    }
}

// -----------------------------------------------------------------------------
extern "C" void kernel_launch(void* const* d_in, const int* in_sizes, int n_in,
                              void* d_out, int out_size, void* d_ws, size_t ws_size,
                              hipStream_t stream) {
    (void)in_sizes; (void)n_in; (void)out_size; (void)ws_size;
    const float* x      = (const float*)d_in[0];
    const float* weight = (const float*)d_in[1];
    const float* ow     = (const float*)d_in[2];
    const float* ob     = (const float*)d_in[3];
    float* out = (float*)d_out;

    unsigned short* offs_b = (unsigned short*)d_ws;            // 2*SP*96 bf16 = 42.5MB
    float* xTf             = (float*)(offs_b + (size_t)2 * SP * OST);  // 14.2MB f32
    unsigned short* Bf     = (unsigned short*)(xTf + (size_t)2 * SP * 16); // 43008 bf16
    unsigned short* Wf     = Bf + 43008;                       // 14336 bf16

    prep_xTf<<<864, 256, 0, stream>>>(x, xTf);
    prep_bfrag<<<168, 256, 0, stream>>>(ow, Bf);
    prep_wfrag<<<56, 256, 0, stream>>>(weight, Wf);
    offs_conv_mfma<<<3456, 256, 0, stream>>>(xTf, Bf, ob, offs_b);
    deform_fused<<<6912, 448, 0, stream>>>(xTf, Wf, offs_b, out);
}

// Round 14
// 156.982 us; speedup vs baseline: 2.0160x; 2.0160x over previous
//
#include <hip/hip_runtime.h>
#include <hip/hip_fp16.h>

#define SDIM 48
#define SP   110592           // 48^3
#define C_IN 16
#define O_OUT 32
#define T27  27
#define OST  96               // offs row stride (channel-last, 81 used, 96 padded)
#define OLROW 100             // offset-LDS row stride (ush) -> conflict-free
#define CPST 36               // Cp row stride (floats) -> 2-way-max banks

typedef __attribute__((ext_vector_type(8))) _Float16 f16x8;
typedef __attribute__((ext_vector_type(4))) float f32x4;

__device__ __forceinline__ float h2f(unsigned short u) {
    return __half2float(__builtin_bit_cast(__half, u));
}
__device__ __forceinline__ unsigned short f2h(float f) {
    __half h = __float2half(f);            // RNE
    return __builtin_bit_cast(unsigned short, h);
}

// ---------- Kernel 0a: x [n][c][sp] fp32 -> xT [n][sp][c] f16 ----------------
__global__ __launch_bounds__(256)
void prep_xT(const float* __restrict__ x, unsigned short* __restrict__ xT) {
    __shared__ float l[256 * 17];
    const int tid = threadIdx.x;
    const int b   = blockIdx.x;          // 0..863
    const int n   = b / 432;
    const int sp0 = (b - n * 432) * 256;
    #pragma unroll
    for (int c = 0; c < 16; ++c)
        l[tid * 17 + c] = x[((size_t)(n * 16 + c)) * SP + sp0 + tid];
    __syncthreads();
    unsigned int u[8];
    #pragma unroll
    for (int q = 0; q < 8; ++q) {
        unsigned short a  = f2h(l[tid * 17 + 2 * q]);
        unsigned short bb = f2h(l[tid * 17 + 2 * q + 1]);
        u[q] = (unsigned int)a | ((unsigned int)bb << 16);
    }
    uint4* dst = (uint4*)(xT + ((size_t)(n * SP + sp0 + tid)) * 16);
    dst[0] = make_uint4(u[0], u[1], u[2], u[3]);
    dst[1] = make_uint4(u[4], u[5], u[6], u[7]);
}

// ---------- Kernel 0b: pack offset-conv weights into B-fragment layout (f16) -
__global__ __launch_bounds__(256)
void prep_bfrag(const float* __restrict__ ow, unsigned short* __restrict__ Bf) {
    int idx = blockIdx.x * 256 + threadIdx.x;     // 0..43007
    int r    = idx & 7;
    int lane = (idx >> 3) & 63;
    int snt  = idx >> 9;                          // s*6+nt, 0..83
    int s = snt / 6, nt = snt - s * 6;
    int kk  = ((lane >> 4) << 3) + r;
    int g   = nt * 16 + (lane & 15);
    int tap = 2 * s + (kk >> 4);
    int c   = kk & 15;
    float v = 0.f;
    if (tap < 27 && g < 81) v = ow[((size_t)(g * 16 + c)) * 27 + tap];
    Bf[idx] = f2h(v);
}

// ---------- Kernel 0c: pack einsum weights into B-frag layout (14 k-steps) ---
__global__ __launch_bounds__(256)
void prep_wfrag(const float* __restrict__ w, unsigned short* __restrict__ Wf) {
    int idx = blockIdx.x * 256 + threadIdx.x;     // 0..14335
    int r    = idx & 7;
    int lane = (idx >> 3) & 63;
    int snt  = idx >> 9;                          // s*2+nt, 0..27
    int s = snt >> 1, nt = snt & 1;
    int kk  = ((lane >> 4) << 3) + r;
    int o   = nt * 16 + (lane & 15);
    int tap = 2 * s + (kk >> 4);
    int c   = kk & 15;
    float v = 0.f;
    if (tap < 27) v = w[((size_t)(o * 16 + c)) * 27 + tap];
    Wf[idx] = f2h(v);
}

// ---------- Kernel 1: offset conv as implicit-GEMM MFMA (f16) ----------------
// Output: offs[n][sp][96] f16 channel-last, contiguous 12KB tile store.
__global__ __launch_bounds__(256)
void offs_conv_mfma(const unsigned short* __restrict__ xT,
                    const unsigned short* __restrict__ Bf,
                    const float* __restrict__ ob,
                    unsigned short* __restrict__ offs) {
    __shared__ unsigned short Alds[256 * 8];      // 4KB staging
    __shared__ unsigned short Tl[64 * 104];       // 13KB epilogue transpose
    const int tid  = threadIdx.x;
    const int lane = tid & 63;
    const int wid  = tid >> 6;
    // XCD-aware chunked swizzle: 3456 = 8 x 432
    const int bid  = (blockIdx.x & 7) * 432 + (blockIdx.x >> 3);
    const int m    = tid & 63;
    const int n    = (bid >= 1728) ? 1 : 0;
    const int sp   = bid * 64 + m - n * SP;
    const int z    = sp / 2304;
    const int rem  = sp - z * 2304;
    const int y    = rem / 48;
    const int xx   = rem - y * 48;
    const int tapoff = wid >> 1;
    const int half   = wid & 1;

    auto stage_load = [&](int s) -> uint4 {
        int tap = 2 * s + tapoff;
        int kd = tap / 9;
        int t2 = tap - kd * 9;
        int kh = t2 / 3;
        int kw = t2 - kh * 3;
        int di = z + kd - 1, hi = y + kh - 1, wi = xx + kw - 1;
        bool ok = (tap < 27) && ((unsigned)di < 48u) && ((unsigned)hi < 48u) &&
                  ((unsigned)wi < 48u);
        uint4 v = make_uint4(0u, 0u, 0u, 0u);
        if (ok) {
            size_t off = ((size_t)(n * SP + (di * 2304 + hi * 48 + wi))) * 16 + half * 8;
            v = *(const uint4*)(xT + off);
        }
        return v;
    };

    f32x4 acc[6];
    #pragma unroll
    for (int t = 0; t < 6; ++t) acc[t] = (f32x4){0.f, 0.f, 0.f, 0.f};

    uint4 v = stage_load(0);
    for (int s = 0; s < 14; ++s) {
        __syncthreads();
        *(uint4*)&Alds[tid * 8] = v;
        __syncthreads();
        if (s < 13) v = stage_load(s + 1);        // prefetch overlaps MFMA
        f16x8 a = *(const f16x8*)&Alds[(((lane >> 4) * 64) + (wid * 16) + (lane & 15)) * 8];
        const f16x8* bp = (const f16x8*)Bf + (size_t)(s * 6) * 64 + lane;
        #pragma unroll
        for (int nt = 0; nt < 6; ++nt) {
            f16x8 b = bp[nt * 64];
            acc[nt] = __builtin_amdgcn_mfma_f32_16x16x32_f16(a, b, acc[nt], 0, 0, 0);
        }
    }

    // epilogue: bias + f16 into LDS [row][g] (stride 104), then contiguous out
    const int mrow = wid * 16 + ((lane >> 4) << 2);
    #pragma unroll
    for (int nt = 0; nt < 6; ++nt) {
        int g = nt * 16 + (lane & 15);
        float bia = (g < 81) ? ob[g] : 0.f;
        #pragma unroll
        for (int r = 0; r < 4; ++r)
            Tl[(mrow + r) * 104 + g] = f2h(acc[nt][r] + bia);
    }
    __syncthreads();
    unsigned short* dst = offs + (size_t)bid * (64 * OST);
    #pragma unroll
    for (int k = 0; k < 3; ++k) {
        int idx = k * 256 + tid;                  // 0..767 uint4-chunks
        int row = idx / 12;
        int col = (idx - row * 12) * 8;
        uint4 vv = *(const uint4*)&Tl[row * 104 + col];
        *(uint4*)(dst + row * OST + col) = vv;
    }
}

// ---------- Kernel 2: wave-independent fused sampling, f16 + fma_mix ---------
// 448 threads = 7 waves; wave wv owns k-steps {2wv, 2wv+1} for both point
// groups (p = pg*16 + lane&15). Lane samples exactly its A-fragment.
// Interp uses v_fma_mix_f32 (f16 operand selected hi/lo from the loaded u32):
// 1 op/channel vs 3 ops/2ch of the bf16 unpack path. x stays 16-bit ->
// 3.5MB/image, L2-resident (R13 lesson: f32 copy doesn't fit 4MB XCD L2).
// REGISTER-CAP HISTORY (do not tighten): cap<=64 on this sampler spills
// (R5: FETCH x7, R9: WRITE x5). (448,4) -> cap 128.
__global__ __launch_bounds__(448, 4)
void deform_fused(const unsigned short* __restrict__ xT,
                  const unsigned short* __restrict__ Wf,
                  const unsigned short* __restrict__ offs,
                  float* __restrict__ out) {
    __shared__ unsigned short OLDS[32 * OLROW];   // 6.4KB offsets
    __shared__ float Cp[7 * 32 * CPST];           // 32.3KB partial-C

    const int tid  = threadIdx.x;
    const int lane = tid & 63;
    const int wv   = tid >> 6;                    // wave 0..6
    const int pl   = lane & 15;                   // point-local (A-frag row)
    const int chh  = (lane >> 4) & 1;             // channel half
    const int tl   = lane >> 5;                   // tap-local in k-step
    // XCD-aware chunked swizzle: 6912 = 8 x 864
    const int bid  = (blockIdx.x & 7) * 864 + (blockIdx.x >> 3);
    const int n    = (bid >= 3456) ? 1 : 0;
    const int sp0  = bid * 32 - n * SP;

    // ---- phase 0: coalesced offset preload (32 rows x 96 ush = 384 uint4) --
    if (tid < 384) {
        int row = tid / 12;
        int col = (tid - row * 12) * 8;
        uint4 v = *(const uint4*)(offs + ((size_t)(n * SP + sp0 + row)) * OST + col);
        *(uint4*)&OLDS[row * OLROW + col] = v;
    }
    __syncthreads();

    const uint4* xq4 = (const uint4*)(xT + (size_t)n * SP * 16);

    f32x4 acc[2][2];                              // [pg][ntile]
    #pragma unroll
    for (int a_ = 0; a_ < 2; ++a_)
        #pragma unroll
        for (int b_ = 0; b_ < 2; ++b_) acc[a_][b_] = (f32x4){0.f, 0.f, 0.f, 0.f};

    #pragma unroll
    for (int pg = 0; pg < 2; ++pg) {
        const int p  = pg * 16 + pl;
        const int sp = sp0 + p;
        const int z  = sp / 2304;
        const int rm = sp - z * 2304;
        const int y  = rm / 48;
        const int xx = rm - y * 48;

        #pragma unroll
        for (int s2 = 0; s2 < 2; ++s2) {
            const int s   = 2 * wv + s2;          // k-step 0..13
            const int tap = 2 * s + tl;           // 0..27 (27 = zero pad)
            uint4 au = make_uint4(0u, 0u, 0u, 0u);
            if (tap < 27) {
                const int kd = tap / 9;
                const int t2 = tap - kd * 9;
                const int kh = t2 / 3;
                const int kw = t2 - kh * 3;
                float pd = (float)(z + kd - 1)  + h2f(OLDS[p * OLROW + tap]);
                float ph = (float)(y + kh - 1)  + h2f(OLDS[p * OLROW + 27 + tap]);
                float pw = (float)(xx + kw - 1) + h2f(OLDS[p * OLROW + 54 + tap]);
                float df = floorf(pd), hf = floorf(ph), wf = floorf(pw);
                float fd = pd - df, fh = ph - hf, fw = pw - wf;
                int d0 = (int)df, h0 = (int)hf, w0 = (int)wf;
                float wd0 = ((unsigned)d0       < 48u) ? (1.f - fd) : 0.f;
                float wd1 = ((unsigned)(d0 + 1) < 48u) ? fd : 0.f;
                float wh0 = ((unsigned)h0       < 48u) ? (1.f - fh) : 0.f;
                float wh1 = ((unsigned)(h0 + 1) < 48u) ? fh : 0.f;
                float ww0 = ((unsigned)w0       < 48u) ? (1.f - fw) : 0.f;
                float ww1 = ((unsigned)(w0 + 1) < 48u) ? fw : 0.f;
                int dc0 = min(max(d0,     0), 47) * 2304;
                int dc1 = min(max(d0 + 1, 0), 47) * 2304;
                int hc0 = min(max(h0,     0), 47) * 48;
                int hc1 = min(max(h0 + 1, 0), 47) * 48;
                int wc0 = min(max(w0,     0), 47);
                int wc1 = min(max(w0 + 1, 0), 47);

                float wdh[4] = {wd0 * wh0, wd0 * wh1, wd1 * wh0, wd1 * wh1};
                int   rdh[4] = {dc0 + hc0, dc0 + hc1, dc1 + hc0, dc1 + hc1};

                uint4 cv[8];
                float cw[8];
                #pragma unroll
                for (int jj = 0; jj < 8; ++jj) {
                    int dh = jj >> 1;
                    int ws = jj & 1;
                    int idx = rdh[dh] + (ws ? wc1 : wc0);
                    cv[jj] = xq4[(size_t)idx * 2 + chh];
                    cw[jj] = wdh[dh] * (ws ? ww1 : ww0);
                }

                float sm[8];
                #pragma unroll
                for (int q = 0; q < 8; ++q) sm[q] = 0.f;
                #pragma unroll
                for (int jj = 0; jj < 8; ++jj) {
                    float w_ = cw[jj];
                    unsigned int uu[4] = {cv[jj].x, cv[jj].y, cv[jj].z, cv[jj].w};
                    #pragma unroll
                    for (int q = 0; q < 4; ++q) {
                        asm("v_fma_mix_f32 %0, %1, %2, %0 op_sel:[0,0,0] op_sel_hi:[1,0,0]"
                            : "+v"(sm[2 * q]) : "v"(uu[q]), "v"(w_));
                        asm("v_fma_mix_f32 %0, %1, %2, %0 op_sel:[1,0,0] op_sel_hi:[1,0,0]"
                            : "+v"(sm[2 * q + 1]) : "v"(uu[q]), "v"(w_));
                    }
                }
                unsigned int o0, o1, o2, o3;
                asm("v_cvt_pkrtz_f16_f32 %0, %1, %2" : "=v"(o0) : "v"(sm[0]), "v"(sm[1]));
                asm("v_cvt_pkrtz_f16_f32 %0, %1, %2" : "=v"(o1) : "v"(sm[2]), "v"(sm[3]));
                asm("v_cvt_pkrtz_f16_f32 %0, %1, %2" : "=v"(o2) : "v"(sm[4]), "v"(sm[5]));
                asm("v_cvt_pkrtz_f16_f32 %0, %1, %2" : "=v"(o3) : "v"(sm[6]), "v"(sm[7]));
                au = make_uint4(o0, o1, o2, o3);
            }
            f16x8 a = __builtin_bit_cast(f16x8, au);
            const f16x8* bp = (const f16x8*)Wf + (size_t)(s * 2) * 64 + lane;
            acc[pg][0] = __builtin_amdgcn_mfma_f32_16x16x32_f16(a, bp[0],  acc[pg][0], 0, 0, 0);
            acc[pg][1] = __builtin_amdgcn_mfma_f32_16x16x32_f16(a, bp[64], acc[pg][1], 0, 0, 0);
        }
    }

    // ---- tail: partial-C write + fp32 reduce + store ----
    {
        const int o16 = lane & 15;
        const int m0  = (lane >> 4) << 2;
        #pragma unroll
        for (int pg = 0; pg < 2; ++pg) {
            *(f32x4*)&Cp[(wv * 32 + o16)      * CPST + pg * 16 + m0] = acc[pg][0];
            *(f32x4*)&Cp[(wv * 32 + 16 + o16) * CPST + pg * 16 + m0] = acc[pg][1];
        }
    }
    __syncthreads();

    #pragma unroll
    for (int rep = 0; rep < 3; ++rep) {
        int i = tid + rep * 448;
        if (i < 1024) {
            int o = i >> 5;                       // 0..31
            int m = i & 31;
            float r0 = 0.f;
            #pragma unroll
            for (int w2 = 0; w2 < 7; ++w2)
                r0 += Cp[(w2 * 32 + o) * CPST + m];
            out[((size_t)(n * O_OUT + o)) * SP + sp0 + m] = r0;
        }
    }
}

// -----------------------------------------------------------------------------
extern "C" void kernel_launch(void* const* d_in, const int* in_sizes, int n_in,
                              void* d_out, int out_size, void* d_ws, size_t ws_size,
                              hipStream_t stream) {
    (void)in_sizes; (void)n_in; (void)out_size; (void)ws_size;
    const float* x      = (const float*)d_in[0];
    const float* weight = (const float*)d_in[1];
    const float* ow     = (const float*)d_in[2];
    const float* ob     = (const float*)d_in[3];
    float* out = (float*)d_out;

    unsigned short* offs_b = (unsigned short*)d_ws;            // 2*SP*96 f16 = 42.5MB
    unsigned short* xT     = offs_b + (size_t)2 * SP * OST;    // 2*SP*16 f16 = 7.1MB
    unsigned short* Bf     = xT + (size_t)2 * SP * 16;         // 43008 f16
    unsigned short* Wf     = Bf + 43008;                       // 14336 f16

    prep_xT<<<864, 256, 0, stream>>>(x, xT);
    prep_bfrag<<<168, 256, 0, stream>>>(ow, Bf);
    prep_wfrag<<<56, 256, 0, stream>>>(weight, Wf);
    offs_conv_mfma<<<3456, 256, 0, stream>>>(xT, Bf, ob, offs_b);
    deform_fused<<<6912, 448, 0, stream>>>(xT, Wf, offs_b, out);
}